// Round 7
// baseline (182.671 us; speedup 1.0000x reference)
//
#include <hip/hip_runtime.h>
#include <hip/hip_fp16.h>

typedef int v4i __attribute__((ext_vector_type(4)));

#define QMAXF 127.0f
#define EPSF 1e-8f

// ---------------------------------------------------------------------------
// Per-row symmetric int8 quantization (validated round 1).
// ---------------------------------------------------------------------------
template <bool WEIGHT>
__global__ __launch_bounds__(256) void quant_rows(
    const float* __restrict__ src, signed char* __restrict__ q,
    float* __restrict__ scale, int ncols) {
  const int row = blockIdx.x;
  const int t = threadIdx.x;
  const float4* s4 = (const float4*)(src + (size_t)row * ncols);

  float4 v[4];
  float am = 0.f;
#pragma unroll
  for (int p = 0; p < 4; ++p) {
    v[p] = s4[p * 256 + t];
    am = fmaxf(am, fmaxf(fmaxf(fabsf(v[p].x), fabsf(v[p].y)),
                         fmaxf(fabsf(v[p].z), fabsf(v[p].w))));
  }
#pragma unroll
  for (int off = 32; off > 0; off >>= 1) am = fmaxf(am, __shfl_xor(am, off));
  __shared__ float red[4];
  if ((t & 63) == 0) red[t >> 6] = am;
  __syncthreads();
  am = fmaxf(fmaxf(red[0], red[1]), fmaxf(red[2], red[3]));

  const float s = fmaxf(am, EPSF) / QMAXF;

  uint32_t* qrow = (uint32_t*)(q + (size_t)row * ncols);
#pragma unroll
  for (int p = 0; p < 4; ++p) {
    float fx = fminf(fmaxf(rintf(v[p].x / s), -QMAXF), QMAXF);
    float fy = fminf(fmaxf(rintf(v[p].y / s), -QMAXF), QMAXF);
    float fz = fminf(fmaxf(rintf(v[p].z / s), -QMAXF), QMAXF);
    float fw = fminf(fmaxf(rintf(v[p].w / s), -QMAXF), QMAXF);
    uint32_t packed = ((uint32_t)((int)fx & 0xff)) |
                      ((uint32_t)((int)fy & 0xff) << 8) |
                      ((uint32_t)((int)fz & 0xff) << 16) |
                      ((uint32_t)((int)fw & 0xff) << 24);
    qrow[p * 256 + t] = packed;
  }
  if (t == 0) {
    float so = s;
    if (WEIGHT) so = __half2float(__float2half(s));
    scale[row] = so;
  }
}

// ---------------------------------------------------------------------------
// 256x256 8-wave int8 GEMM.
// Round-7 change vs validated round-6: consumption-ordered reads + pinned
// 2-stage software pipeline per window. lgkmcnt is IN-ORDER: previously the
// first MFMA consumed read #9 of 16, so every MFMA cluster waited for nearly
// the whole CU-wide read burst (sum behavior). Now each window issues
//   [ks0 reads (B then A) + stage issues] SB(0) [ks1 reads] SB(0)
//   [MFMA ks0 (gated lgkm(ks1-count), overlaps ks1 landing) -> MFMA ks1]
// Window/barrier/stage/vmcnt-ledger structure byte-identical to round 6.
// ---------------------------------------------------------------------------
__device__ __forceinline__ void gload16(const void* g, void* l) {
  __builtin_amdgcn_global_load_lds(
      (const __attribute__((address_space(1))) void*)g,
      (__attribute__((address_space(3))) void*)l, 16, 0, 0);
}

#define STAGE_A(dst, br0, ktoff)                                            \
  do {                                                                      \
    gload16(Ap + (size_t)((br0) + lr) * K + (ktoff) + scsw,                 \
            (dst) + ((br0) + lr) * 128 + sc);                               \
    gload16(Ap + (size_t)((br0) + 128 + lr) * K + (ktoff) + scsw,           \
            (dst) + ((br0) + 128 + lr) * 128 + sc);                         \
  } while (0)

#define STAGE_B(dst, nh, ktoff)                                             \
  do {                                                                      \
    const int r_ = (nh)*32 + lr + (lr & 32);                                \
    gload16(Bp + (size_t)(r_) * K + (ktoff) + scsw, (dst) + r_ * 128 + sc); \
    gload16(Bp + (size_t)(r_ + 128) * K + (ktoff) + scsw,                   \
            (dst) + (r_ + 128) * 128 + sc);                                 \
  } while (0)

// A-fragments for half MH, single k-substep ks (4 x ds_read_b128)
#define READ_AF_KS(MH, ks)                                                  \
  _Pragma("unroll") for (int mi = 0; mi < 4; ++mi)                          \
      af[mi][ks] = *(const v4i*)(Ad + (arow + ((MH)*4 + mi) * 16) * 128 +   \
                                 ((ac0 + (ks)*64) ^ axor))

// B-fragments for half NH, single k-substep ks (2 x ds_read_b128)
#define READ_BF_KS(dst, NH, ks)                                             \
  _Pragma("unroll") for (int ni = 0; ni < 2; ++ni)                          \
      dst[ni][ks] = *(const v4i*)(Bd + (brow + ((NH)*2 + ni) * 16) * 128 +  \
                                  ((ac0 + (ks)*64) ^ bxor))

// 16 MFMAs: one k-substep across the full 128x64 wave tile (both B halves)
#define MFMA_KS(MH, ks)                                                     \
  _Pragma("unroll") for (int mi = 0; mi < 4; ++mi) {                        \
    _Pragma("unroll") for (int ni = 0; ni < 2; ++ni) {                      \
      acc[(MH)*4 + mi][ni] = __builtin_amdgcn_mfma_i32_16x16x64_i8(         \
          af[mi][ks], bf0[ni][ks], acc[(MH)*4 + mi][ni], 0, 0, 0);          \
      acc[(MH)*4 + mi][2 + ni] = __builtin_amdgcn_mfma_i32_16x16x64_i8(     \
          af[mi][ks], bf1[ni][ks], acc[(MH)*4 + mi][2 + ni], 0, 0, 0);      \
    }                                                                       \
  }

__global__ __launch_bounds__(512, 2) void gemm_i8(
    const signed char* __restrict__ A,  // xq [M][K]
    const signed char* __restrict__ B,  // wq [N][K]
    const float* __restrict__ xsc,      // [M]
    const float* __restrict__ wsc,      // [N]
    const float* __restrict__ bias,     // [N]
    float* __restrict__ out, int M, int N, int K) {
  __shared__ __align__(16) signed char lds[131072];
  signed char* const ldsA = lds;          // [2][256][128]
  signed char* const ldsB = lds + 65536;  // [2][256][128]

  const int tid = threadIdx.x;
  const int lane = tid & 63;
  const int wid = tid >> 6;  // 0..7
  const int wm = wid >> 2;   // 0..1
  const int wn = wid & 3;    // 0..3
  const int bm0 = blockIdx.x * 256;
  const int bn0 = blockIdx.y * 256;

  const signed char* Ap = A + (size_t)bm0 * K;
  const signed char* Bp = B + (size_t)bn0 * K;

  // staging geometry (per thread): one 16B chunk of a 64-row x 128B block
  const int lr = tid >> 3;                // 0..63 row within 8KB block
  const int sc = (tid & 7) << 4;          // linear dest col byte
  const int scsw = sc ^ ((lr & 7) << 4);  // pre-swizzled SOURCE col

  // read geometry (per lane)
  const int arow = wm * 128 + (lane & 15);
  const int brow = wn * 64 + (lane & 15);
  const int ac0 = (lane >> 4) << 4;  // 16B k-chunk within 64B ksub
  const int axor = (arow & 7) << 4;
  const int bxor = (brow & 7) << 4;

  v4i acc[8][4];
#pragma unroll
  for (int i = 0; i < 8; ++i)
#pragma unroll
    for (int j = 0; j < 4; ++j) acc[i][j] = (v4i){0, 0, 0, 0};

  const int NKT = K >> 7;  // 32 K-tiles of 128 bytes

  // ---- prologue: kt0 fully + {SA0,SB0}(kt1); drain to 4 outstanding ----
  STAGE_A(ldsA, 0, 0);            // SA0(0)
  STAGE_B(ldsB, 0, 0);            // SB0(0)
  STAGE_A(ldsA, 64, 0);           // SA1(0)
  STAGE_B(ldsB, 1, 0);            // SB1(0)
  STAGE_A(ldsA + 32768, 0, 128);  // SA0(1)
  STAGE_B(ldsB + 32768, 0, 128);  // SB0(1)
  asm volatile("s_waitcnt vmcnt(4)" ::: "memory");
  __builtin_amdgcn_sched_barrier(0);
  __builtin_amdgcn_s_barrier();

  for (int kt = 0; kt < NKT; ++kt) {
    const int d = kt & 1;
    const signed char* Ad = ldsA + d * 32768;
    const signed char* Bd = ldsB + d * 32768;
    signed char* const An = ldsA + (d ^ 1) * 32768;
    signed char* const Bn = ldsB + (d ^ 1) * 32768;
    const int ko1 = (kt + 1) << 7;
    const int ko2 = (kt + 2) << 7;

    v4i af[4][2];   // A-half fragments (MH0 in w1, MH1 in w2)
    v4i bf0[2][2];  // B NH=0 fragments (read w1, used w1+w2)
    v4i bf1[2][2];  // B NH=1 fragments (read w1, used w1+w2)

    // ---- window 1: [ks0 reads + stages] | [ks1 reads] | MFMA ks0,ks1 ----
    READ_BF_KS(bf0, 0, 0);  // 2 reads
    READ_BF_KS(bf1, 1, 0);  // 2
    READ_AF_KS(0, 0);       // 4  => 8 ks0 reads
    if (kt + 1 < NKT) {
      STAGE_A(An, 64, ko1);
      STAGE_B(Bn, 1, ko1);
    }
    __builtin_amdgcn_sched_barrier(0);
    READ_BF_KS(bf0, 0, 1);
    READ_BF_KS(bf1, 1, 1);
    READ_AF_KS(0, 1);       // 8 ks1 reads (in flight during MFMA ks0)
    __builtin_amdgcn_sched_barrier(0);
    __builtin_amdgcn_s_setprio(1);
    MFMA_KS(0, 0);          // gated on ks0 reads only (lgkm(8))
    MFMA_KS(0, 1);
    __builtin_amdgcn_s_setprio(0);
    __builtin_amdgcn_s_barrier();

    // ---- window 2: [ks0 A reads + stages] | [ks1 A reads] | MFMA ----
    READ_AF_KS(1, 0);       // 4 ks0 reads
    if (kt + 2 < NKT) {
      STAGE_A((signed char*)Ad, 0, ko2);
      STAGE_B((signed char*)Bd, 0, ko2);
    }
    __builtin_amdgcn_sched_barrier(0);
    READ_AF_KS(1, 1);       // 4 ks1 reads
    __builtin_amdgcn_sched_barrier(0);
    __builtin_amdgcn_s_setprio(1);
    MFMA_KS(1, 0);          // gated on ks0 reads only (lgkm(4))
    MFMA_KS(1, 1);
    __builtin_amdgcn_s_setprio(0);
    // counted drain in steady state; full drain once staging stops
    if (kt < NKT - 2) {
      asm volatile("s_waitcnt vmcnt(4)" ::: "memory");
    } else {
      asm volatile("s_waitcnt vmcnt(0)" ::: "memory");
    }
    __builtin_amdgcn_sched_barrier(0);
    __builtin_amdgcn_s_barrier();
  }

  // ---- epilogue: dequant + fp16-roundtripped bias, fp32 store ----
#pragma unroll
  for (int mi = 0; mi < 8; ++mi) {
    const int m0 = bm0 + wm * 128 + mi * 16 + ((lane >> 4) << 2);
    const float4 xs = *(const float4*)&xsc[m0];
    const float xsv[4] = {xs.x, xs.y, xs.z, xs.w};
#pragma unroll
    for (int ni = 0; ni < 4; ++ni) {
      const int n = bn0 + wn * 64 + ni * 16 + (lane & 15);
      const float wsn = wsc[n];
      const float bn_ = __half2float(__float2half(bias[n]));
#pragma unroll
      for (int r = 0; r < 4; ++r) {
        out[(size_t)(m0 + r) * N + n] =
            (float)acc[mi][ni][r] * xsv[r] * wsn + bn_;
      }
    }
  }
}

extern "C" void kernel_launch(void* const* d_in, const int* in_sizes, int n_in,
                              void* d_out, int out_size, void* d_ws,
                              size_t ws_size, hipStream_t stream) {
  const float* x = (const float*)d_in[0];     // [M][K] fp32
  const float* w = (const float*)d_in[1];     // [N][K] fp32
  const float* bias = (const float*)d_in[2];  // [N] fp32
  float* out = (float*)d_out;

  const int K = 4096;
  const int Nw = in_sizes[1] / K;  // 4096
  const int M = in_sizes[0] / K;   // 8192

  signed char* wq = (signed char*)d_ws;
  signed char* xq = wq + (size_t)Nw * K;
  float* wsc = (float*)(xq + (size_t)M * K);
  float* xsc = wsc + Nw;

  quant_rows<true><<<Nw, 256, 0, stream>>>(w, wq, wsc, K);
  quant_rows<false><<<M, 256, 0, stream>>>(x, xq, xsc, K);

  dim3 g2(M / 256, Nw / 256, 1);
  gemm_i8<<<g2, 512, 0, stream>>>(xq, wq, xsc, wsc, bias, out, M, Nw, K);
}